// Round 8
// baseline (812.640 us; speedup 1.0000x reference)
//
#include <hip/hip_runtime.h>

// Problem constants (from reference): B=128, L=1024, D=2048, f32 in/out.
constexpr int Bc = 128;
constexpr int Lc = 1024;
constexpr int Dc = 2048;

constexpr int THREADS   = 256;
constexpr int VEC       = 4;                   // float4 per thread
constexpr int DCOLS_BLK = THREADS * VEC;       // 1024 columns per block
constexpr int DBLKS     = Dc / DCOLS_BLK;      // 2
constexpr int NL        = 8;                   // row-interleave groups (full residency)

typedef float v4f __attribute__((ext_vector_type(4)));

// part: [Bc][DBLKS][NL][DCOLS_BLK] partials (8 MB), cnt: [Bc*DBLKS] after it.
constexpr size_t PART_ELEMS = (size_t)Bc * DBLKS * NL * DCOLS_BLK;
constexpr size_t CNT_OFF    = PART_ELEMS * sizeof(float);          // 8 MB
constexpr size_t WS_NEEDED  = CNT_OFF + (size_t)Bc * DBLKS * sizeof(unsigned);

// ---------------- Fused: stream + partial store + last-block reduce --------
__global__ __launch_bounds__(THREADS) void avg_pool_fused(
    const float* __restrict__ feat,
    const int*   __restrict__ lengths,
    float*       __restrict__ part,
    unsigned*    __restrict__ cnt,     // pre-zeroed each call
    float*       __restrict__ out)
{
    int bid  = blockIdx.x;
    int lc   = bid % NL;
    int dblk = (bid / NL) % DBLKS;
    int b    = bid / (NL * DBLKS);

    int len = lengths[b];
    int eff = (len > 0) ? len : Lc;

    int t   = (int)threadIdx.x;
    int col = dblk * DCOLS_BLK + t * VEC;
    const float* p = feat + (size_t)b * Lc * Dc + (size_t)lc * Dc + col;

    float ax = 0.f, ay = 0.f, az = 0.f, aw = 0.f;
    #pragma unroll 4
    for (int l = lc; l < eff; l += NL, p += (size_t)NL * Dc) {
        v4f v = __builtin_nontemporal_load(reinterpret_cast<const v4f*>(p));
        ax += v.x; ay += v.y; az += v.z; aw += v.w;
    }

    // Store this block's partial (plain stores so the fence orders them).
    size_t grp = (size_t)b * DBLKS + dblk;
    {
        v4f r; r.x = ax; r.y = ay; r.z = az; r.w = aw;
        *reinterpret_cast<v4f*>(part + (grp * NL + lc) * DCOLS_BLK + t * VEC) = r;
    }

    __threadfence();                   // release: partial visible device-wide
    __syncthreads();                   // all threads' stores+fences done

    __shared__ unsigned s_old;
    if (t == 0) s_old = atomicAdd(&cnt[grp], 1u);
    __syncthreads();

    if (s_old == NL - 1) {
        __threadfence();               // acquire: see all 8 partials
        // Fixed-order sum over all 8 partials -> bitwise-deterministic
        // regardless of which block performs the reduce.
        float sx = 0.f, sy = 0.f, sz = 0.f, sw = 0.f;
        const float* base = part + grp * NL * DCOLS_BLK + t * VEC;
        #pragma unroll
        for (int lc2 = 0; lc2 < NL; ++lc2) {
            v4f v = *reinterpret_cast<const v4f*>(base + (size_t)lc2 * DCOLS_BLK);
            sx += v.x; sy += v.y; sz += v.z; sw += v.w;
        }
        float inv = 1.0f / (float)eff;
        v4f o4; o4.x = sx * inv; o4.y = sy * inv; o4.z = sz * inv; o4.w = sw * inv;
        *reinterpret_cast<v4f*>(out + (size_t)b * Dc + col) = o4;
    }
}

// ---------------- Fallback: atomic single-kernel path (needs no ws) --------
__global__ __launch_bounds__(THREADS) void avg_pool_atomic(
    const float* __restrict__ feat,
    const int*   __restrict__ lengths,
    float*       __restrict__ out)
{
    int bid  = blockIdx.x;
    int lc   = bid % NL;
    int dblk = (bid / NL) % DBLKS;
    int b    = bid / (NL * DBLKS);

    int len = lengths[b];
    int eff = (len > 0) ? len : Lc;

    int col = dblk * DCOLS_BLK + (int)threadIdx.x * VEC;
    const float* p = feat + (size_t)b * Lc * Dc + (size_t)lc * Dc + col;

    float ax = 0.f, ay = 0.f, az = 0.f, aw = 0.f;
    #pragma unroll 4
    for (int l = lc; l < eff; l += NL, p += (size_t)NL * Dc) {
        v4f v = __builtin_nontemporal_load(reinterpret_cast<const v4f*>(p));
        ax += v.x; ay += v.y; az += v.z; aw += v.w;
    }

    float inv = 1.0f / (float)eff;
    float* o = out + (size_t)b * Dc + col;
    atomicAdd(o + 0, ax * inv);
    atomicAdd(o + 1, ay * inv);
    atomicAdd(o + 2, az * inv);
    atomicAdd(o + 3, aw * inv);
}

extern "C" void kernel_launch(void* const* d_in, const int* in_sizes, int n_in,
                              void* d_out, int out_size, void* d_ws, size_t ws_size,
                              hipStream_t stream)
{
    const float* feat    = (const float*)d_in[0];
    const int*   lengths = (const int*)d_in[1];
    float*       out     = (float*)d_out;

    if (ws_size >= WS_NEEDED) {
        float*    part = (float*)d_ws;
        unsigned* cnt  = (unsigned*)((char*)d_ws + CNT_OFF);
        // Counters must start at 0 every call (ws poisoned 0xAA once,
        // never re-poisoned): tiny 1 KB memset node.
        (void)hipMemsetAsync(cnt, 0, (size_t)Bc * DBLKS * sizeof(unsigned), stream);
        avg_pool_fused<<<dim3(Bc * DBLKS * NL), dim3(THREADS), 0, stream>>>(
            feat, lengths, part, cnt, out);
    } else {
        (void)hipMemsetAsync(out, 0, (size_t)out_size * sizeof(float), stream);
        avg_pool_atomic<<<dim3(Bc * DBLKS * NL), dim3(THREADS), 0, stream>>>(
            feat, lengths, out);
    }
}

// Round 9
// 104.911 us; speedup vs baseline: 7.7460x; 7.7460x over previous
//
#include <hip/hip_runtime.h>

// Problem constants (from reference): B=128, L=1024, D=2048, f32 in/out.
constexpr int Bc = 128;
constexpr int Lc = 1024;
constexpr int Dc = 2048;

constexpr int THREADS   = 256;
constexpr int VEC       = 4;                   // float4 per thread
constexpr int DCOLS_BLK = THREADS * VEC;       // 1024 columns per block
constexpr int DBLKS     = Dc / DCOLS_BLK;      // 2

typedef float v4f __attribute__((ext_vector_type(4)));

// ---------------- Stage 1: stream + per-block partial sums (no atomics) ----
// part layout: [Bc][DBLKS][NLT][DCOLS_BLK]
template <int NLT>
__global__ __launch_bounds__(THREADS) void avg_pool_stage1(
    const float* __restrict__ feat,
    const int*   __restrict__ lengths,
    float*       __restrict__ part)
{
    int bid  = blockIdx.x;
    int lc   = bid % NLT;
    int dblk = (bid / NLT) % DBLKS;
    int b    = bid / (NLT * DBLKS);

    int len = lengths[b];
    int eff = (len > 0) ? len : Lc;

    int t   = (int)threadIdx.x;
    int col = dblk * DCOLS_BLK + t * VEC;
    const float* p = feat + (size_t)b * Lc * Dc + (size_t)lc * Dc + col;

    float ax = 0.f, ay = 0.f, az = 0.f, aw = 0.f;
    #pragma unroll 4
    for (int l = lc; l < eff; l += NLT, p += (size_t)NLT * Dc) {
        v4f v = __builtin_nontemporal_load(reinterpret_cast<const v4f*>(p));
        ax += v.x; ay += v.y; az += v.z; aw += v.w;
    }

    v4f r; r.x = ax; r.y = ay; r.z = az; r.w = aw;
    float* o = part + (((size_t)b * DBLKS + dblk) * NLT + lc) * DCOLS_BLK + t * VEC;
    __builtin_nontemporal_store(r, reinterpret_cast<v4f*>(o));
}

// ---------------- Stage 2: reduce NLT partials, scale, overwrite d_out -----
template <int NLT>
__global__ __launch_bounds__(THREADS) void avg_pool_stage2(
    const float* __restrict__ part,
    const int*   __restrict__ lengths,
    float*       __restrict__ out)
{
    int g     = blockIdx.x * THREADS + (int)threadIdx.x;  // v4f index over out
    int b     = g / (Dc / VEC);
    int v     = g % (Dc / VEC);
    int dblk  = v / (DCOLS_BLK / VEC);
    int colin = (v % (DCOLS_BLK / VEC)) * VEC;

    int len = lengths[b];
    int eff = (len > 0) ? len : Lc;
    float inv = 1.0f / (float)eff;

    const float* base = part + (((size_t)b * DBLKS + dblk) * NLT) * DCOLS_BLK + colin;

    float ax = 0.f, ay = 0.f, az = 0.f, aw = 0.f;
    #pragma unroll
    for (int lc = 0; lc < NLT; ++lc) {
        v4f p = *reinterpret_cast<const v4f*>(base + (size_t)lc * DCOLS_BLK);
        ax += p.x; ay += p.y; az += p.z; aw += p.w;
    }
    v4f r; r.x = ax * inv; r.y = ay * inv; r.z = az * inv; r.w = aw * inv;
    *reinterpret_cast<v4f*>(out + (size_t)b * Dc + (size_t)v * VEC) = r;
}

// ---------------- Fallback: atomic single-kernel path (needs no ws) --------
__global__ __launch_bounds__(THREADS) void avg_pool_atomic(
    const float* __restrict__ feat,
    const int*   __restrict__ lengths,
    float*       __restrict__ out)
{
    constexpr int NLT = 8;
    int bid  = blockIdx.x;
    int lc   = bid % NLT;
    int dblk = (bid / NLT) % DBLKS;
    int b    = bid / (NLT * DBLKS);

    int len = lengths[b];
    int eff = (len > 0) ? len : Lc;

    int col = dblk * DCOLS_BLK + (int)threadIdx.x * VEC;
    const float* p = feat + (size_t)b * Lc * Dc + (size_t)lc * Dc + col;

    float ax = 0.f, ay = 0.f, az = 0.f, aw = 0.f;
    #pragma unroll 4
    for (int l = lc; l < eff; l += NLT, p += (size_t)NLT * Dc) {
        v4f v = __builtin_nontemporal_load(reinterpret_cast<const v4f*>(p));
        ax += v.x; ay += v.y; az += v.z; aw += v.w;
    }

    float inv = 1.0f / (float)eff;
    float* o = out + (size_t)b * Dc + col;
    atomicAdd(o + 0, ax * inv);
    atomicAdd(o + 1, ay * inv);
    atomicAdd(o + 2, az * inv);
    atomicAdd(o + 3, aw * inv);
}

extern "C" void kernel_launch(void* const* d_in, const int* in_sizes, int n_in,
                              void* d_out, int out_size, void* d_ws, size_t ws_size,
                              hipStream_t stream)
{
    const float* feat    = (const float*)d_in[0];
    const int*   lengths = (const int*)d_in[1];
    float*       out     = (float*)d_out;

    auto ws_for = [](int nl) {
        return (size_t)Bc * DBLKS * nl * DCOLS_BLK * sizeof(float);
    };

    if (ws_size >= ws_for(16)) {
        // 2x oversubscription (4096 blocks vs 2048 resident) -> scheduler
        // backfill smooths the variable-length tail.
        float* part = (float*)d_ws;
        avg_pool_stage1<16><<<dim3(Bc * DBLKS * 16), dim3(THREADS), 0, stream>>>(
            feat, lengths, part);
        avg_pool_stage2<16><<<dim3(Bc * (Dc / VEC) / THREADS), dim3(THREADS), 0, stream>>>(
            part, lengths, out);
    } else if (ws_size >= ws_for(8)) {
        float* part = (float*)d_ws;
        avg_pool_stage1<8><<<dim3(Bc * DBLKS * 8), dim3(THREADS), 0, stream>>>(
            feat, lengths, part);
        avg_pool_stage2<8><<<dim3(Bc * (Dc / VEC) / THREADS), dim3(THREADS), 0, stream>>>(
            part, lengths, out);
    } else {
        (void)hipMemsetAsync(out, 0, (size_t)out_size * sizeof(float), stream);
        avg_pool_atomic<<<dim3(Bc * DBLKS * 8), dim3(THREADS), 0, stream>>>(
            feat, lengths, out);
    }
}

// Round 10
// 98.822 us; speedup vs baseline: 8.2233x; 1.0616x over previous
//
#include <hip/hip_runtime.h>

// Problem constants (from reference): B=128, L=1024, D=2048, f32 in/out.
constexpr int Bc = 128;
constexpr int Lc = 1024;
constexpr int Dc = 2048;

constexpr int THREADS   = 256;
constexpr int VEC       = 4;                   // float4 per thread
constexpr int DCOLS_BLK = THREADS * VEC;       // 1024 columns per block
constexpr int DBLKS     = Dc / DCOLS_BLK;      // 2
constexpr int NL        = 8;                   // row-interleave groups (full residency)

typedef float v4f __attribute__((ext_vector_type(4)));

// ---------------- Stage 1: stream + per-block partial sums (no atomics) ----
// part layout: [Bc][DBLKS][NL][DCOLS_BLK]  (8 MB)
__global__ __launch_bounds__(THREADS) void avg_pool_stage1(
    const float* __restrict__ feat,
    const int*   __restrict__ lengths,
    float*       __restrict__ part)
{
    int bid  = blockIdx.x;
    int lc   = bid % NL;
    int dblk = (bid / NL) % DBLKS;
    int b    = bid / (NL * DBLKS);

    int len = lengths[b];
    int eff = (len > 0) ? len : Lc;

    int t   = (int)threadIdx.x;
    int col = dblk * DCOLS_BLK + t * VEC;
    const float* p = feat + (size_t)b * Lc * Dc + (size_t)lc * Dc + col;

    float ax = 0.f, ay = 0.f, az = 0.f, aw = 0.f;
    #pragma unroll 4
    for (int l = lc; l < eff; l += NL, p += (size_t)NL * Dc) {
        v4f v = __builtin_nontemporal_load(reinterpret_cast<const v4f*>(p));
        ax += v.x; ay += v.y; az += v.z; aw += v.w;
    }

    v4f r; r.x = ax; r.y = ay; r.z = az; r.w = aw;
    float* o = part + (((size_t)b * DBLKS + dblk) * NL + lc) * DCOLS_BLK + t * VEC;
    __builtin_nontemporal_store(r, reinterpret_cast<v4f*>(o));
}

// ---------------- Stage 2: reduce 8 partials, scale, overwrite d_out -------
__global__ __launch_bounds__(THREADS) void avg_pool_stage2(
    const float* __restrict__ part,
    const int*   __restrict__ lengths,
    float*       __restrict__ out)
{
    int g     = blockIdx.x * THREADS + (int)threadIdx.x;  // v4f index over out
    int b     = g / (Dc / VEC);
    int v     = g % (Dc / VEC);
    int dblk  = v / (DCOLS_BLK / VEC);
    int colin = (v % (DCOLS_BLK / VEC)) * VEC;

    int len = lengths[b];
    int eff = (len > 0) ? len : Lc;
    float inv = 1.0f / (float)eff;

    const float* base = part + (((size_t)b * DBLKS + dblk) * NL) * DCOLS_BLK + colin;

    float ax = 0.f, ay = 0.f, az = 0.f, aw = 0.f;
    #pragma unroll
    for (int lc = 0; lc < NL; ++lc) {
        v4f p = *reinterpret_cast<const v4f*>(base + (size_t)lc * DCOLS_BLK);
        ax += p.x; ay += p.y; az += p.z; aw += p.w;
    }
    v4f r; r.x = ax * inv; r.y = ay * inv; r.z = az * inv; r.w = aw * inv;
    *reinterpret_cast<v4f*>(out + (size_t)b * Dc + (size_t)v * VEC) = r;
}

// ---------------- Fallback: atomic single-kernel path (needs no ws) --------
__global__ __launch_bounds__(THREADS) void avg_pool_atomic(
    const float* __restrict__ feat,
    const int*   __restrict__ lengths,
    float*       __restrict__ out)
{
    int bid  = blockIdx.x;
    int lc   = bid % NL;
    int dblk = (bid / NL) % DBLKS;
    int b    = bid / (NL * DBLKS);

    int len = lengths[b];
    int eff = (len > 0) ? len : Lc;

    int col = dblk * DCOLS_BLK + (int)threadIdx.x * VEC;
    const float* p = feat + (size_t)b * Lc * Dc + (size_t)lc * Dc + col;

    float ax = 0.f, ay = 0.f, az = 0.f, aw = 0.f;
    #pragma unroll 4
    for (int l = lc; l < eff; l += NL, p += (size_t)NL * Dc) {
        v4f v = __builtin_nontemporal_load(reinterpret_cast<const v4f*>(p));
        ax += v.x; ay += v.y; az += v.z; aw += v.w;
    }

    float inv = 1.0f / (float)eff;
    float* o = out + (size_t)b * Dc + col;
    atomicAdd(o + 0, ax * inv);
    atomicAdd(o + 1, ay * inv);
    atomicAdd(o + 2, az * inv);
    atomicAdd(o + 3, aw * inv);
}

extern "C" void kernel_launch(void* const* d_in, const int* in_sizes, int n_in,
                              void* d_out, int out_size, void* d_ws, size_t ws_size,
                              hipStream_t stream)
{
    const float* feat    = (const float*)d_in[0];
    const int*   lengths = (const int*)d_in[1];
    float*       out     = (float*)d_out;

    const size_t ws_needed = (size_t)Bc * DBLKS * NL * DCOLS_BLK * sizeof(float);

    if (ws_size >= ws_needed) {
        float* part = (float*)d_ws;
        avg_pool_stage1<<<dim3(Bc * DBLKS * NL), dim3(THREADS), 0, stream>>>(
            feat, lengths, part);
        avg_pool_stage2<<<dim3(Bc * (Dc / VEC) / THREADS), dim3(THREADS), 0, stream>>>(
            part, lengths, out);
    } else {
        (void)hipMemsetAsync(out, 0, (size_t)out_size * sizeof(float), stream);
        avg_pool_atomic<<<dim3(Bc * DBLKS * NL), dim3(THREADS), 0, stream>>>(
            feat, lengths, out);
    }
}